// Round 4
// baseline (256.316 us; speedup 1.0000x reference)
//
#include <hip/hip_runtime.h>
#include <math.h>

// out = x + gate * ( sb*wedge(x,csum) + e0 * ss*scalar(x,csum) )
// csum = 3*x[t] - x[t-1] - x[t-2] - x[t-4]   (linearity collapses the shifts)
//
// R4: rolling-history strips. One wave owns 8 consecutive t-rows; rows
// t-1..t-4 live in a 4-slot register ring (unroll-4 -> compile-time slots),
// so each row needs only 4 current-row loads + 4 stores; gate_w is loaded
// once per wave. R3 evidence: 24 VMEM/row + per-row latency exposure was the
// invariant (R2/R3 moved <=11%); fill kernel proves 6.5 TB/s is reachable.
//
// Layout per row: lane handles float4s at lane + 64*m (m=0..3), fully
// coalesced. Quad 4c..4c+3 co-owns a 16-blade chunk; cross-blade values via
// quad-broadcast ds_swizzle. Row reductions = 6-step wave butterflies.

constexpr int T_DIM = 4096;
constexpr int D_DIM = 1024;
constexpr int ROWS_PER_WAVE = 8;   // strip length; 32768/(4*8)=1024 blocks

constexpr int QB0 = 0x8000;  // quad broadcast lane 0
constexpr int QB1 = 0x8055;  // quad broadcast lane 1
constexpr int QB2 = 0x80AA;  // quad broadcast lane 2

template <int PAT>
__device__ __forceinline__ float swz(float v) {
    return __int_as_float(__builtin_amdgcn_ds_swizzle(__float_as_int(v), PAT));
}

__device__ __forceinline__ float sigmoidf(float z) {
    return 1.0f / (1.0f + __expf(-z));
}

__global__ __launch_bounds__(256, 3) void clifford_kernel(
    const float* __restrict__ x,
    const float* __restrict__ gate_w,
    const float* __restrict__ gate_b,
    const float* __restrict__ scalar_w,
    const float* __restrict__ bivec_w,
    float* __restrict__ out,
    int BT)
{
    const int lane = threadIdx.x & 63;
    const int wid  = blockIdx.x * 4 + (threadIdx.x >> 6);
    const int r0   = wid * ROWS_PER_WAVE;          // strip start row
    if (r0 >= BT) return;
    const int b  = r0 >> 12;                       // r0 / T_DIM
    const int t0 = r0 & (T_DIM - 1);               // strip start t (mult of 8)
    const size_t brow = (size_t)b * T_DIM;
    const int sub = lane & 3;

    // per-m element offset within a row
    int off[4];
    #pragma unroll
    for (int m = 0; m < 4; ++m) off[m] = (lane << 2) + (m << 8);

    // ---- once per wave: gate_w chunk + history warmup (rows t0-1..t0-4) ----
    float4 gw4[4];
    #pragma unroll
    for (int m = 0; m < 4; ++m) gw4[m] = *(const float4*)(gate_w + off[m]);

    // ring[slot][m]; at phase p of the unrolled loop (row t):
    //   t-1 -> ring[(p+3)&3], t-2 -> ring[(p+2)&3], t-4 -> ring[p]
    // after computing, ring[p] <- x[t].  Initial: ring[3-k+1]... concretely
    //   ring[3]=x[t0-1], ring[2]=x[t0-2], ring[1]=x[t0-3], ring[0]=x[t0-4]
    float4 ring[4][4];
    #pragma unroll
    for (int k = 1; k <= 4; ++k) {
        const float* rp = x + (brow + ((t0 - k) & (T_DIM - 1))) * D_DIM;
        #pragma unroll
        for (int m = 0; m < 4; ++m) ring[4 - k][m] = *(const float4*)(rp + off[m]);
    }

    const float ss = sigmoidf(scalar_w[0]);
    const float sb = sigmoidf(bivec_w[0]);
    const float gb = gate_b[0];

    // C0 diagonal signs for this lane's 4 blades
    // full table: {1,1,1,-1, 1,-1,-1,-1, -1,1,1,1, 1,1,1,-1}
    float4 ws;
    if      (sub == 0) ws = make_float4( 1.f,  1.f,  1.f, -1.f);
    else if (sub == 1) ws = make_float4( 1.f, -1.f, -1.f, -1.f);
    else if (sub == 2) ws = make_float4(-1.f,  1.f,  1.f,  1.f);
    else               ws = make_float4( 1.f,  1.f,  1.f, -1.f);
    const float m3  = (sub == 0) ? 1.f : 0.f;   // elem3 <- k=3
    const float a1  = (sub == 1) ? 1.f : 0.f;   // elem1<-k=5, elem2<-k=6
    const float a2  = (sub == 2) ? 1.f : 0.f;   // elem1<-k=9, elem2<-k=10
    const float m12 = (sub == 3) ? 1.f : 0.f;   // elem0 <- k=12
    const bool is_lane0 = (lane == 0);

    const float* __restrict__ xrow = x   + (size_t)r0 * D_DIM;
    float*       __restrict__ orow = out + (size_t)r0 * D_DIM;

    for (int it = 0; it < ROWS_PER_WAVE; it += 4) {
        #pragma unroll
        for (int p = 0; p < 4; ++p) {
            // ---- load current row (the only per-row global reads) ----
            float4 cur[4];
            #pragma unroll
            for (int m = 0; m < 4; ++m)
                cur[m] = *(const float4*)(xrow + off[m]);

            float gate_part = 0.f, sc_part = 0.f;
            float4 dl[4];

            #pragma unroll
            for (int m = 0; m < 4; ++m) {
                const float4 xv = cur[m];
                const float4 p1 = ring[(p + 3) & 3][m];
                const float4 p2 = ring[(p + 2) & 3][m];
                const float4 p4 = ring[p & 3][m];
                float4 cs;
                cs.x = 3.f * xv.x - p1.x - p2.x - p4.x;
                cs.y = 3.f * xv.y - p1.y - p2.y - p4.y;
                cs.z = 3.f * xv.z - p1.z - p2.z - p4.z;
                cs.w = 3.f * xv.w - p1.w - p2.w - p4.w;

                gate_part += xv.x * gw4[m].x + xv.y * gw4[m].y
                           + xv.z * gw4[m].z + xv.w * gw4[m].w;
                sc_part   += ws.x * (xv.x * cs.x) + ws.y * (xv.y * cs.y)
                           + ws.z * (xv.z * cs.z) + ws.w * (xv.w * cs.w);

                const float x1  = swz<QB0>(xv.y), x2  = swz<QB0>(xv.z);
                const float x4b = swz<QB1>(xv.x), x8b = swz<QB2>(xv.x);
                const float c1  = swz<QB0>(cs.y), c2  = swz<QB0>(cs.z);
                const float c4b = swz<QB1>(cs.x), c8b = swz<QB2>(cs.x);

                const float w3  = x1 * c2  - x2  * c1;    // k=3
                const float w5  = x1 * c4b - x4b * c1;    // k=5
                const float w6  = x2 * c4b - x4b * c2;    // k=6
                const float w9  = x1 * c8b - x8b * c1;    // k=9
                const float w10 = x2 * c8b - x8b * c2;    // k=10
                const float w12 = x4b * c8b - x8b * c4b;  // k=12

                dl[m] = make_float4(m12 * w12,
                                    a1 * w5 + a2 * w9,
                                    a1 * w6 + a2 * w10,
                                    m3 * w3);
            }

            // ---- wave butterfly reduce (wave == row) ----
            #pragma unroll
            for (int o = 32; o > 0; o >>= 1) {
                gate_part += __shfl_xor(gate_part, o, 64);
                sc_part   += __shfl_xor(sc_part,   o, 64);
            }
            const float gate = sigmoidf(gate_part + gb);
            const float gsb  = gate * sb;

            // ---- epilogue + store ----
            #pragma unroll
            for (int m = 0; m < 4; ++m) {
                float4 o4;
                o4.x = cur[m].x + gsb * dl[m].x;
                o4.y = cur[m].y + gsb * dl[m].y;
                o4.z = cur[m].z + gsb * dl[m].z;
                o4.w = cur[m].w + gsb * dl[m].w;
                if (m == 0 && is_lane0) o4.x += gate * ss * sc_part;
                *(float4*)(orow + off[m]) = o4;
            }

            // ---- rotate history: slot p takes current row ----
            #pragma unroll
            for (int m = 0; m < 4; ++m) ring[p & 3][m] = cur[m];

            xrow += D_DIM;
            orow += D_DIM;
        }
    }
}

extern "C" void kernel_launch(void* const* d_in, const int* in_sizes, int n_in,
                              void* d_out, int out_size, void* d_ws, size_t ws_size,
                              hipStream_t stream) {
    const float* x  = (const float*)d_in[0];
    const float* gw = (const float*)d_in[1];
    const float* gb = (const float*)d_in[2];
    const float* sw = (const float*)d_in[3];
    const float* bw = (const float*)d_in[4];
    float* out = (float*)d_out;

    const int BT = in_sizes[0] / D_DIM;                   // 32768 rows
    const int waves = (BT + ROWS_PER_WAVE - 1) / ROWS_PER_WAVE;
    const int blocks = (waves + 3) / 4;                   // 4 waves per block
    hipLaunchKernelGGL(clifford_kernel, dim3(blocks), dim3(256), 0, stream,
                       x, gw, gb, sw, bw, out, BT);
}

// Round 5
// 242.254 us; speedup vs baseline: 1.0580x; 1.0580x over previous
//
#include <hip/hip_runtime.h>
#include <math.h>

// out = x + gate * ( sb*wedge(x,csum) + e0 * ss*scalar(x,csum) )
// csum = 3*x[t] - x[t-1] - x[t-2] - x[t-4]   (linearity collapses the shifts)
//
// R5: async LDS staging. Evidence R1-R4: latency-bound (no pipe >25%, wave
// lifetime ~22k cy by Little's law); compiler always sinks register loads
// (VGPR 44/48/84) so per-wave MLP never materializes. Fix: block = 4
// consecutive t-rows; stage the 8-row union (t0-4..t0+3, 32 KB) to LDS via
// global_load_lds width=16 (DMA, no VGPR dests -> cannot be serialized by
// regalloc), ONE barrier, then all operand reads are LDS ds_read_b128.
// 4-5 blocks/CU overlap staging with compute.
//
// Per row: lane handles float4s at lane + 64*m (m=0..3), coalesced. Quad
// 4c..4c+3 co-owns a 16-blade chunk; cross-blade via quad-broadcast
// ds_swizzle. Row reductions = 6-step wave butterflies (wave == row).

constexpr int T_DIM = 4096;
constexpr int D_DIM = 1024;
constexpr int HALO = 4;
constexpr int ROWS_PER_BLOCK = 4;
constexpr int TILE_ROWS = ROWS_PER_BLOCK + HALO;   // 8 rows -> 32 KB LDS

constexpr int QB0 = 0x8000;  // quad broadcast lane 0
constexpr int QB1 = 0x8055;  // quad broadcast lane 1
constexpr int QB2 = 0x80AA;  // quad broadcast lane 2

template <int PAT>
__device__ __forceinline__ float swz(float v) {
    return __int_as_float(__builtin_amdgcn_ds_swizzle(__float_as_int(v), PAT));
}

__device__ __forceinline__ float sigmoidf(float z) {
    return 1.0f / (1.0f + __expf(-z));
}

__global__ __launch_bounds__(256, 4) void clifford_kernel(
    const float* __restrict__ x,
    const float* __restrict__ gate_w,
    const float* __restrict__ gate_b,
    const float* __restrict__ scalar_w,
    const float* __restrict__ bivec_w,
    float* __restrict__ out,
    int BT)
{
    __shared__ __align__(16) float tile[TILE_ROWS * D_DIM];   // 32 KB

    // XCD swizzle: consecutive-t blocks on the same XCD so the 4-row halo
    // (previous block's rows) hits that XCD's L2.
    int blk = blockIdx.x;
    if ((gridDim.x & 7) == 0) {
        const int per = gridDim.x >> 3;
        blk = (blockIdx.x & 7) * per + (blockIdx.x >> 3);
    }

    const int lane = threadIdx.x & 63;
    const int w    = threadIdx.x >> 6;              // wave id = row within block
    const int r0   = blk * ROWS_PER_BLOCK;          // first output row
    if (r0 >= BT) return;                           // block-uniform
    const int b  = r0 >> 12;
    const int t0 = r0 & (T_DIM - 1);
    const size_t brow = (size_t)b * T_DIM;
    const int sub = lane & 3;

    // ---- stage rows t0-4 .. t0+3 into LDS (32 segments x 1 KB, async) ----
    // segment s: local row lr = s>>2, quarter part = s&3.
    #pragma unroll
    for (int r = 0; r < 8; ++r) {
        const int s    = r * 4 + w;
        const int lr   = s >> 2;
        const int part = s & 3;
        const int t    = (t0 - HALO + lr) & (T_DIM - 1);
        const float* g = x + (brow + t) * (size_t)D_DIM + part * 256 + lane * 4;
        __builtin_amdgcn_global_load_lds(
            (const __attribute__((address_space(1))) unsigned int*)g,
            (__attribute__((address_space(3))) unsigned int*)(tile + s * 256),
            16, 0, 0);
    }

    // ---- overlap with staging: gate_w chunk + scalars into registers ----
    float4 gv[4];
    #pragma unroll
    for (int m = 0; m < 4; ++m)
        gv[m] = *(const float4*)(gate_w + lane * 4 + m * 256);
    const float ss = sigmoidf(scalar_w[0]);
    const float sb = sigmoidf(bivec_w[0]);
    const float gb = gate_b[0];

    // C0 diagonal signs for this lane's 4 blades
    // full table: {1,1,1,-1, 1,-1,-1,-1, -1,1,1,1, 1,1,1,-1}
    float4 wsg;
    if      (sub == 0) wsg = make_float4( 1.f,  1.f,  1.f, -1.f);
    else if (sub == 1) wsg = make_float4( 1.f, -1.f, -1.f, -1.f);
    else if (sub == 2) wsg = make_float4(-1.f,  1.f,  1.f,  1.f);
    else               wsg = make_float4( 1.f,  1.f,  1.f, -1.f);
    const float m3  = (sub == 0) ? 1.f : 0.f;   // elem3 <- k=3
    const float a1  = (sub == 1) ? 1.f : 0.f;   // elem1<-k=5, elem2<-k=6
    const float a2  = (sub == 2) ? 1.f : 0.f;   // elem1<-k=9, elem2<-k=10
    const float m12 = (sub == 3) ? 1.f : 0.f;   // elem0 <- k=12

    __syncthreads();   // single bulk drain of the staging DMA

    // ---- compute: wave w owns row t0+w; local row lr = HALO + w ----
    const float4* __restrict__ t4 = (const float4*)tile;
    const int lr = HALO + w;
    // float4-granular row bases (256 float4 per row)
    const int b0 = lr * 256;          // x[t]
    const int b1 = (lr - 1) * 256;    // x[t-1]
    const int b2 = (lr - 2) * 256;    // x[t-2]
    const int b4 = (lr - 4) * 256;    // x[t-4]

    float gate_part = 0.f, sc_part = 0.f;
    float4 cur[4], dl[4];

    #pragma unroll
    for (int m = 0; m < 4; ++m) {
        const int e = m * 64 + lane;
        const float4 xv = t4[b0 + e];
        const float4 p1 = t4[b1 + e];
        const float4 p2 = t4[b2 + e];
        const float4 p4 = t4[b4 + e];
        cur[m] = xv;

        float4 cs;
        cs.x = 3.f * xv.x - p1.x - p2.x - p4.x;
        cs.y = 3.f * xv.y - p1.y - p2.y - p4.y;
        cs.z = 3.f * xv.z - p1.z - p2.z - p4.z;
        cs.w = 3.f * xv.w - p1.w - p2.w - p4.w;

        gate_part += xv.x * gv[m].x + xv.y * gv[m].y
                   + xv.z * gv[m].z + xv.w * gv[m].w;
        sc_part   += wsg.x * (xv.x * cs.x) + wsg.y * (xv.y * cs.y)
                   + wsg.z * (xv.z * cs.z) + wsg.w * (xv.w * cs.w);

        const float x1  = swz<QB0>(xv.y), x2  = swz<QB0>(xv.z);
        const float x4b = swz<QB1>(xv.x), x8b = swz<QB2>(xv.x);
        const float c1  = swz<QB0>(cs.y), c2  = swz<QB0>(cs.z);
        const float c4b = swz<QB1>(cs.x), c8b = swz<QB2>(cs.x);

        const float w3  = x1 * c2  - x2  * c1;    // k=3  (e12)
        const float w5  = x1 * c4b - x4b * c1;    // k=5  (e13)
        const float w6  = x2 * c4b - x4b * c2;    // k=6  (e23)
        const float w9  = x1 * c8b - x8b * c1;    // k=9  (e14)
        const float w10 = x2 * c8b - x8b * c2;    // k=10 (e24)
        const float w12 = x4b * c8b - x8b * c4b;  // k=12 (e34)

        dl[m] = make_float4(m12 * w12,
                            a1 * w5 + a2 * w9,
                            a1 * w6 + a2 * w10,
                            m3 * w3);
    }

    // ---- wave butterfly reduce (wave == row) ----
    #pragma unroll
    for (int o = 32; o > 0; o >>= 1) {
        gate_part += __shfl_xor(gate_part, o, 64);
        sc_part   += __shfl_xor(sc_part,   o, 64);
    }
    const float gate = sigmoidf(gate_part + gb);
    const float gsb  = gate * sb;

    // ---- epilogue + coalesced store ----
    float* __restrict__ orow = out + (size_t)(r0 + w) * D_DIM;
    #pragma unroll
    for (int m = 0; m < 4; ++m) {
        float4 o4;
        o4.x = cur[m].x + gsb * dl[m].x;
        o4.y = cur[m].y + gsb * dl[m].y;
        o4.z = cur[m].z + gsb * dl[m].z;
        o4.w = cur[m].w + gsb * dl[m].w;
        if (m == 0 && lane == 0) o4.x += gate * ss * sc_part;  // d==0
        *(float4*)(orow + lane * 4 + m * 256) = o4;
    }
}

extern "C" void kernel_launch(void* const* d_in, const int* in_sizes, int n_in,
                              void* d_out, int out_size, void* d_ws, size_t ws_size,
                              hipStream_t stream) {
    const float* x  = (const float*)d_in[0];
    const float* gw = (const float*)d_in[1];
    const float* gb = (const float*)d_in[2];
    const float* sw = (const float*)d_in[3];
    const float* bw = (const float*)d_in[4];
    float* out = (float*)d_out;

    const int BT = in_sizes[0] / D_DIM;                       // 32768 rows
    const int blocks = (BT + ROWS_PER_BLOCK - 1) / ROWS_PER_BLOCK;  // 8192
    hipLaunchKernelGGL(clifford_kernel, dim3(blocks), dim3(256), 0, stream,
                       x, gw, gb, sw, bw, out, BT);
}